// Round 4
// baseline (216.445 us; speedup 1.0000x reference)
//
#include <hip/hip_runtime.h>

#define N_NODES 50000
#define E_EDGES 250000
#define IN_F 9
#define OUT_F 84
#define GROUPS 21            // OUT_F / 4
#define BN_EPS 1e-5f

// workspace layout (floats):
//   [0, 168)                  : BN stats (sum[84], sumsq[84])
//   [256, 256 + N*18)         : S buffer — per node: S0[9] then S1[9]
#define STATS_OFF 0
#define S_OFF 256
#define S_FLOATS (N_NODES * 18)
#define ZERO_FLOATS (S_OFF + S_FLOATS)   // 900256, multiple of 4

// node kernel grid: total threads divisible by 21 so g = gid % 21 is fixed
// per thread across grid-stride iterations (enables register stat accum).
#define NODE_BLOCKS 504          // 504*256 = 129024 = 21 * 6144
#define NODE_THREADS 256
#define NODE_TOTAL (NODE_BLOCKS * NODE_THREADS)

// ---------------------------------------------------------------------------
// K0: zero stats + S buffer (ws is poisoned 0xAA before every launch)
// ---------------------------------------------------------------------------
__global__ void zero_ws_kernel(float4* __restrict__ ws4) {
    int i = blockIdx.x * blockDim.x + threadIdx.x;
    if (i < ZERO_FLOATS / 4)
        ws4[i] = make_float4(0.f, 0.f, 0.f, 0.f);
}

// ---------------------------------------------------------------------------
// K1: edge scatter, algebraically collapsed (EDIM==1):
//   S0[dst] += x[src]          (9 floats)
//   S1[dst] += ea[e] * x[src]  (9 floats)
// thread per (edge, i in 0..8) -> 2.25M threads, 2 atomics each.
// ---------------------------------------------------------------------------
__global__ void scatter_kernel(const float* __restrict__ x,
                               const int* __restrict__ ei,
                               const float* __restrict__ ea,
                               float* __restrict__ S) {
    int gid = blockIdx.x * blockDim.x + threadIdx.x;
    if (gid >= E_EDGES * IN_F) return;
    int e = gid / IN_F;
    int i = gid - e * IN_F;

    int src = ei[e];
    int dst = ei[E_EDGES + e];
    float a = ea[e];
    float xv = x[src * IN_F + i];

    atomicAdd(&S[dst * 18 + i], xv);
    atomicAdd(&S[dst * 18 + 9 + i], a * xv);
}

// ---------------------------------------------------------------------------
// K2: fused node kernel + BN stats.
//   out[n,:] = x[n]@root + S1[n]@W + S0[n]@B + bias
// grid-stride, thread-fixed channel group g = gid0 % 21; per-thread register
// sum/sumsq -> LDS bins -> one global atomic per stat entry per block.
// ---------------------------------------------------------------------------
__global__ void node_kernel(const float* __restrict__ x,
                            const float* __restrict__ S,
                            const float* __restrict__ nw,
                            const float* __restrict__ nb,
                            const float* __restrict__ root,
                            const float* __restrict__ bias,
                            float* __restrict__ out,
                            float* __restrict__ stats) {
    __shared__ __align__(16) float4 Ws[IN_F * GROUPS];
    __shared__ __align__(16) float4 Bs[IN_F * GROUPS];
    __shared__ __align__(16) float4 Rs[IN_F * GROUPS];
    __shared__ __align__(16) float4 bs[GROUPS];
    __shared__ float sbin[2 * OUT_F];   // sum[84], sumsq[84]
    for (int t = threadIdx.x; t < IN_F * GROUPS; t += blockDim.x) {
        Ws[t] = ((const float4*)nw)[t];
        Bs[t] = ((const float4*)nb)[t];
        Rs[t] = ((const float4*)root)[t];
    }
    if (threadIdx.x < GROUPS) bs[threadIdx.x] = ((const float4*)bias)[threadIdx.x];
    if (threadIdx.x < 2 * OUT_F) sbin[threadIdx.x] = 0.0f;
    __syncthreads();

    const int gid0 = blockIdx.x * blockDim.x + threadIdx.x;
    const int g = gid0 % GROUPS;        // fixed: NODE_TOTAL % 21 == 0

    float4 s = make_float4(0.f, 0.f, 0.f, 0.f);
    float4 q = make_float4(0.f, 0.f, 0.f, 0.f);

    for (int gid = gid0; gid < N_NODES * GROUPS; gid += NODE_TOTAL) {
        int n = gid / GROUPS;

        float xv[IN_F], s0[IN_F], s1[IN_F];
#pragma unroll
        for (int i = 0; i < IN_F; ++i) {
            xv[i] = x[n * IN_F + i];
            s0[i] = S[n * 18 + i];
            s1[i] = S[n * 18 + 9 + i];
        }

        float4 acc = bs[g];
#pragma unroll
        for (int i = 0; i < IN_F; ++i) {
            float4 r = Rs[i * GROUPS + g];
            float4 w = Ws[i * GROUPS + g];
            float4 b = Bs[i * GROUPS + g];
            acc.x += xv[i] * r.x + s1[i] * w.x + s0[i] * b.x;
            acc.y += xv[i] * r.y + s1[i] * w.y + s0[i] * b.y;
            acc.z += xv[i] * r.z + s1[i] * w.z + s0[i] * b.z;
            acc.w += xv[i] * r.w + s1[i] * w.w + s0[i] * b.w;
        }
        *(float4*)&out[gid * 4] = acc;   // gid*4 == n*84 + g*4, 16B aligned

        s.x += acc.x; s.y += acc.y; s.z += acc.z; s.w += acc.w;
        q.x += acc.x * acc.x; q.y += acc.y * acc.y;
        q.z += acc.z * acc.z; q.w += acc.w * acc.w;
    }

    // fold per-thread stats into LDS bins (g is thread-fixed)
    atomicAdd(&sbin[g * 4 + 0], s.x);
    atomicAdd(&sbin[g * 4 + 1], s.y);
    atomicAdd(&sbin[g * 4 + 2], s.z);
    atomicAdd(&sbin[g * 4 + 3], s.w);
    atomicAdd(&sbin[OUT_F + g * 4 + 0], q.x);
    atomicAdd(&sbin[OUT_F + g * 4 + 1], q.y);
    atomicAdd(&sbin[OUT_F + g * 4 + 2], q.z);
    atomicAdd(&sbin[OUT_F + g * 4 + 3], q.w);
    __syncthreads();

    if (threadIdx.x < 2 * OUT_F)
        atomicAdd(&stats[threadIdx.x], sbin[threadIdx.x]);
}

// ---------------------------------------------------------------------------
// K3: BatchNorm normalize in place (fully coalesced float4).
// ---------------------------------------------------------------------------
__global__ void norm_kernel(float* __restrict__ out,
                            const float* __restrict__ stats,
                            const float* __restrict__ gamma,
                            const float* __restrict__ beta) {
    int gid = blockIdx.x * blockDim.x + threadIdx.x;
    if (gid >= N_NODES * GROUPS) return;
    int g = gid % GROUPS;

    const float inv_n = 1.0f / (float)N_NODES;
    float4 s = *(const float4*)&stats[g * 4];
    float4 q = *(const float4*)&stats[OUT_F + g * 4];
    float4 gm = *(const float4*)&gamma[g * 4];
    float4 bt = *(const float4*)&beta[g * 4];

    float4 v = *(float4*)&out[gid * 4];

    float mx = s.x * inv_n, my = s.y * inv_n, mz = s.z * inv_n, mw = s.w * inv_n;
    float ix = rsqrtf(q.x * inv_n - mx * mx + BN_EPS) * gm.x;
    float iy = rsqrtf(q.y * inv_n - my * my + BN_EPS) * gm.y;
    float iz = rsqrtf(q.z * inv_n - mz * mz + BN_EPS) * gm.z;
    float iw = rsqrtf(q.w * inv_n - mw * mw + BN_EPS) * gm.w;

    v.x = (v.x - mx) * ix + bt.x;
    v.y = (v.y - my) * iy + bt.y;
    v.z = (v.z - mz) * iz + bt.z;
    v.w = (v.w - mw) * iw + bt.w;

    *(float4*)&out[gid * 4] = v;
}

extern "C" void kernel_launch(void* const* d_in, const int* in_sizes, int n_in,
                              void* d_out, int out_size, void* d_ws, size_t ws_size,
                              hipStream_t stream) {
    const float* x     = (const float*)d_in[0];
    const int*   ei    = (const int*)d_in[1];     // int64 in ref -> int32 here
    const float* ea    = (const float*)d_in[2];
    const float* nw    = (const float*)d_in[3];
    const float* nb    = (const float*)d_in[4];
    const float* root  = (const float*)d_in[5];
    const float* bias  = (const float*)d_in[6];
    const float* gamma = (const float*)d_in[7];
    const float* beta  = (const float*)d_in[8];
    float*       out   = (float*)d_out;

    float* ws    = (float*)d_ws;
    float* stats = ws + STATS_OFF;   // 168 floats
    float* S     = ws + S_OFF;       // N*18 floats (3.6 MB)

    const int nthreads_node    = N_NODES * GROUPS;   // 1,050,000
    const int nthreads_scatter = E_EDGES * IN_F;     // 2,250,000

    zero_ws_kernel<<<(ZERO_FLOATS / 4 + 255) / 256, 256, 0, stream>>>((float4*)ws);
    scatter_kernel<<<(nthreads_scatter + 255) / 256, 256, 0, stream>>>(x, ei, ea, S);
    node_kernel<<<NODE_BLOCKS, NODE_THREADS, 0, stream>>>(x, S, nw, nb, root, bias, out, stats);
    norm_kernel<<<(nthreads_node + 255) / 256, 256, 0, stream>>>(out, stats, gamma, beta);
}

// Round 5
// 132.128 us; speedup vs baseline: 1.6381x; 1.6381x over previous
//
#include <hip/hip_runtime.h>

#define N_NODES 50000
#define E_EDGES 250000
#define IN_F 9
#define OUT_F 84
#define GROUPS 21            // OUT_F / 4
#define BN_EPS 1e-5f

// workspace layout (4-byte units):
//   [0, 168)             : BN stats (sum[84], sumsq[84])        float
//   [256, 50256)         : head[N]  per-dst linked-list head    int
//   [50256, 300256)      : next[E]  linked-list next pointers   int
//   [300256, 1200256)    : S[N*18]  per node: S0[9], S1[9]      float
#define STATS_OFF 0
#define HEAD_OFF  256
#define NEXT_OFF  50256
#define S_OFF     300256

// stats kernel grid: 336*256 = 86016 = 21*4096 -> g = gid%21 thread-fixed
#define STATS_BLOCKS 336
#define STATS_THREADS 256
#define STATS_TOTAL (STATS_BLOCKS * STATS_THREADS)

// ---------------------------------------------------------------------------
// K0: init ws — stats = 0, head = -1. (next/S fully overwritten later; no init)
// ---------------------------------------------------------------------------
__global__ void init_ws_kernel(float* __restrict__ stats, int* __restrict__ head) {
    int i = blockIdx.x * blockDim.x + threadIdx.x;
    if (i < 2 * OUT_F) stats[i] = 0.0f;
    if (i < N_NODES) head[i] = -1;
}

// ---------------------------------------------------------------------------
// K1: build per-destination linked list. One atomicExch per edge.
// ---------------------------------------------------------------------------
__global__ void build_list_kernel(const int* __restrict__ ei,
                                  int* __restrict__ head,
                                  int* __restrict__ next) {
    int e = blockIdx.x * blockDim.x + threadIdx.x;
    if (e >= E_EDGES) return;
    int dst = ei[E_EDGES + e];
    next[e] = atomicExch(&head[dst], e);
}

// ---------------------------------------------------------------------------
// K2: gather — thread per (node, i in 0..8). Walk the chain, accumulate
//   S0[n,i] = sum_e x[src_e, i],  S1[n,i] = sum_e ea_e * x[src_e, i]
// in registers. No atomics. 9 sibling lanes walk the same chain (broadcast
// loads of ei/ea/next); x[src*9+i] is a coalesced 36B gather.
// ---------------------------------------------------------------------------
__global__ void gather_kernel(const float* __restrict__ x,
                              const int* __restrict__ ei,
                              const float* __restrict__ ea,
                              const int* __restrict__ head,
                              const int* __restrict__ next,
                              float* __restrict__ S) {
    int gid = blockIdx.x * blockDim.x + threadIdx.x;
    if (gid >= N_NODES * IN_F) return;
    int n = gid / IN_F;
    int i = gid - n * IN_F;

    float s0 = 0.0f, s1 = 0.0f;
    int e = head[n];
    while (e >= 0) {
        int src = ei[e];
        float a = ea[e];
        float xv = x[src * IN_F + i];
        s0 += xv;
        s1 += a * xv;
        e = next[e];
    }
    S[n * 18 + i] = s0;
    S[n * 18 + 9 + i] = s1;
}

// ---------------------------------------------------------------------------
// K3: node kernel (R3-proven single-shot form — no loop-carried state).
//   out[n,:] = x[n]@root + S1[n]@W + S0[n]@B + bias
// ---------------------------------------------------------------------------
__global__ void node_kernel(const float* __restrict__ x,
                            const float* __restrict__ S,
                            const float* __restrict__ nw,
                            const float* __restrict__ nb,
                            const float* __restrict__ root,
                            const float* __restrict__ bias,
                            float* __restrict__ out) {
    __shared__ __align__(16) float4 Ws[IN_F * GROUPS];
    __shared__ __align__(16) float4 Bs[IN_F * GROUPS];
    __shared__ __align__(16) float4 Rs[IN_F * GROUPS];
    __shared__ __align__(16) float4 bs[GROUPS];
    for (int t = threadIdx.x; t < IN_F * GROUPS; t += blockDim.x) {
        Ws[t] = ((const float4*)nw)[t];
        Bs[t] = ((const float4*)nb)[t];
        Rs[t] = ((const float4*)root)[t];
    }
    if (threadIdx.x < GROUPS) bs[threadIdx.x] = ((const float4*)bias)[threadIdx.x];
    __syncthreads();

    int gid = blockIdx.x * blockDim.x + threadIdx.x;
    if (gid >= N_NODES * GROUPS) return;
    int n = gid / GROUPS;
    int g = gid - n * GROUPS;

    float xv[IN_F], s0[IN_F], s1[IN_F];
#pragma unroll
    for (int i = 0; i < IN_F; ++i) {
        xv[i] = x[n * IN_F + i];
        s0[i] = S[n * 18 + i];
        s1[i] = S[n * 18 + 9 + i];
    }

    float4 acc = bs[g];
#pragma unroll
    for (int i = 0; i < IN_F; ++i) {
        float4 r = Rs[i * GROUPS + g];
        float4 w = Ws[i * GROUPS + g];
        float4 b = Bs[i * GROUPS + g];
        acc.x += xv[i] * r.x + s1[i] * w.x + s0[i] * b.x;
        acc.y += xv[i] * r.y + s1[i] * w.y + s0[i] * b.y;
        acc.z += xv[i] * r.z + s1[i] * w.z + s0[i] * b.z;
        acc.w += xv[i] * r.w + s1[i] * w.w + s0[i] * b.w;
    }
    *(float4*)&out[gid * 4] = acc;   // gid*4 == n*84 + g*4, 16B aligned
}

// ---------------------------------------------------------------------------
// K4: BN stats, coalesced. Grid-stride over float4 elements; total threads
// divisible by 21 -> g = gid%21 fixed per thread -> register accumulation,
// then LDS fold and one global atomic per stat entry per block.
// ---------------------------------------------------------------------------
__global__ void stats_kernel(const float* __restrict__ out,
                             float* __restrict__ stats) {
    __shared__ float sbin[2 * OUT_F];
    if (threadIdx.x < 2 * OUT_F) sbin[threadIdx.x] = 0.0f;
    __syncthreads();

    const int gid0 = blockIdx.x * blockDim.x + threadIdx.x;
    const int g = gid0 % GROUPS;       // fixed: STATS_TOTAL % 21 == 0

    float4 s = make_float4(0.f, 0.f, 0.f, 0.f);
    float4 q = make_float4(0.f, 0.f, 0.f, 0.f);
    for (int f = gid0; f < N_NODES * GROUPS; f += STATS_TOTAL) {
        float4 v = ((const float4*)out)[f];
        s.x += v.x; s.y += v.y; s.z += v.z; s.w += v.w;
        q.x += v.x * v.x; q.y += v.y * v.y;
        q.z += v.z * v.z; q.w += v.w * v.w;
    }

    atomicAdd(&sbin[g * 4 + 0], s.x);
    atomicAdd(&sbin[g * 4 + 1], s.y);
    atomicAdd(&sbin[g * 4 + 2], s.z);
    atomicAdd(&sbin[g * 4 + 3], s.w);
    atomicAdd(&sbin[OUT_F + g * 4 + 0], q.x);
    atomicAdd(&sbin[OUT_F + g * 4 + 1], q.y);
    atomicAdd(&sbin[OUT_F + g * 4 + 2], q.z);
    atomicAdd(&sbin[OUT_F + g * 4 + 3], q.w);
    __syncthreads();

    if (threadIdx.x < 2 * OUT_F)
        atomicAdd(&stats[threadIdx.x], sbin[threadIdx.x]);
}

// ---------------------------------------------------------------------------
// K5: BatchNorm normalize in place (fully coalesced float4).
// ---------------------------------------------------------------------------
__global__ void norm_kernel(float* __restrict__ out,
                            const float* __restrict__ stats,
                            const float* __restrict__ gamma,
                            const float* __restrict__ beta) {
    int gid = blockIdx.x * blockDim.x + threadIdx.x;
    if (gid >= N_NODES * GROUPS) return;
    int g = gid % GROUPS;

    const float inv_n = 1.0f / (float)N_NODES;
    float4 s = *(const float4*)&stats[g * 4];
    float4 q = *(const float4*)&stats[OUT_F + g * 4];
    float4 gm = *(const float4*)&gamma[g * 4];
    float4 bt = *(const float4*)&beta[g * 4];

    float4 v = *(float4*)&out[gid * 4];

    float mx = s.x * inv_n, my = s.y * inv_n, mz = s.z * inv_n, mw = s.w * inv_n;
    float ix = rsqrtf(q.x * inv_n - mx * mx + BN_EPS) * gm.x;
    float iy = rsqrtf(q.y * inv_n - my * my + BN_EPS) * gm.y;
    float iz = rsqrtf(q.z * inv_n - mz * mz + BN_EPS) * gm.z;
    float iw = rsqrtf(q.w * inv_n - mw * mw + BN_EPS) * gm.w;

    v.x = (v.x - mx) * ix + bt.x;
    v.y = (v.y - my) * iy + bt.y;
    v.z = (v.z - mz) * iz + bt.z;
    v.w = (v.w - mw) * iw + bt.w;

    *(float4*)&out[gid * 4] = v;
}

extern "C" void kernel_launch(void* const* d_in, const int* in_sizes, int n_in,
                              void* d_out, int out_size, void* d_ws, size_t ws_size,
                              hipStream_t stream) {
    const float* x     = (const float*)d_in[0];
    const int*   ei    = (const int*)d_in[1];     // int64 in ref -> int32 here
    const float* ea    = (const float*)d_in[2];
    const float* nw    = (const float*)d_in[3];
    const float* nb    = (const float*)d_in[4];
    const float* root  = (const float*)d_in[5];
    const float* bias  = (const float*)d_in[6];
    const float* gamma = (const float*)d_in[7];
    const float* beta  = (const float*)d_in[8];
    float*       out   = (float*)d_out;

    float* wsf   = (float*)d_ws;
    int*   wsi   = (int*)d_ws;
    float* stats = wsf + STATS_OFF;   // 168 floats
    int*   head  = wsi + HEAD_OFF;    // N ints
    int*   next  = wsi + NEXT_OFF;    // E ints
    float* S     = wsf + S_OFF;       // N*18 floats (3.6 MB)

    init_ws_kernel<<<(N_NODES + 255) / 256, 256, 0, stream>>>(stats, head);
    build_list_kernel<<<(E_EDGES + 255) / 256, 256, 0, stream>>>(ei, head, next);
    gather_kernel<<<(N_NODES * IN_F + 255) / 256, 256, 0, stream>>>(x, ei, ea, head, next, S);
    node_kernel<<<(N_NODES * GROUPS + 255) / 256, 256, 0, stream>>>(x, S, nw, nb, root, bias, out);
    stats_kernel<<<STATS_BLOCKS, STATS_THREADS, 0, stream>>>(out, stats);
    norm_kernel<<<(N_NODES * GROUPS + 255) / 256, 256, 0, stream>>>(out, stats, gamma, beta);
}